// Round 1
// baseline (379.132 us; speedup 1.0000x reference)
//
#include <hip/hip_runtime.h>
#include <cstdint>

typedef __attribute__((ext_vector_type(8))) short bf16x8;
typedef __attribute__((ext_vector_type(4))) float f32x4;
typedef __attribute__((ext_vector_type(4))) unsigned short u16x4;
typedef __attribute__((ext_vector_type(8))) unsigned short u16x8;

typedef __attribute__((address_space(1))) unsigned int gu32_t;
typedef __attribute__((address_space(3))) unsigned int lu32_t;

#define BATCH 8192
#define DIN 1024
#define DH 1024
#define KD 2048   // DIN + DH
#define ND 4096   // 4 * DH

__device__ __forceinline__ unsigned short f2bf(float f) {
    union { float f; unsigned int u; } v; v.f = f;
    unsigned int u = v.u;
    u += 0x7fffu + ((u >> 16) & 1u);   // RNE (finite inputs only)
    return (unsigned short)(u >> 16);
}
__device__ __forceinline__ float bf2f(unsigned short s) {
    union { unsigned int u; float f; } v; v.u = ((unsigned int)s) << 16;
    return v.f;
}
__device__ __forceinline__ float sigmoidf_(float x) {
    return 1.0f / (1.0f + __expf(-x));
}
__device__ __forceinline__ float tanhf_(float x) {
    float xc = fminf(fmaxf(x, -15.0f), 15.0f);
    float e2 = __expf(2.0f * xc);
    return (e2 - 1.0f) / (e2 + 1.0f);
}

// ---------------- convert x,h -> A (8192 x 2048 bf16) ----------------
__global__ void __launch_bounds__(256) convert_A(const float* __restrict__ x,
                                                 const float* __restrict__ h,
                                                 unsigned short* __restrict__ A) {
    const int t = blockIdx.x * 256 + threadIdx.x;       // 2,097,152 tasks
    const int64_t off = (int64_t)t * 8;
    const int row = (int)(off >> 11);
    const int k = (int)(off & 2047);
    const float* src = (k < DIN) ? (x + (int64_t)row * DIN + k)
                                 : (h + (int64_t)row * DH + (k - DIN));
    f32x4 v0 = *(const f32x4*)src;
    f32x4 v1 = *(const f32x4*)(src + 4);
    u16x8 o;
    o[0] = f2bf(v0[0]); o[1] = f2bf(v0[1]); o[2] = f2bf(v0[2]); o[3] = f2bf(v0[3]);
    o[4] = f2bf(v1[0]); o[5] = f2bf(v1[1]); o[6] = f2bf(v1[2]); o[7] = f2bf(v1[3]);
    *(u16x8*)(A + off) = o;
}

// ---------------- convert weights -> B (4096 x 2048 bf16, K-major) ----------------
__global__ void __launch_bounds__(256) convert_B(
        const float* __restrict__ Wii, const float* __restrict__ Wih,
        const float* __restrict__ Wfi, const float* __restrict__ Wfh,
        const float* __restrict__ Wgi, const float* __restrict__ Wgh,
        const float* __restrict__ Woi, const float* __restrict__ Woh,
        unsigned short* __restrict__ B) {
    const int t = blockIdx.x * 256 + threadIdx.x;       // 1,048,576 tasks
    const int64_t off = (int64_t)t * 8;
    const int brow = (int)(off >> 11);
    const int k = (int)(off & 2047);
    const int gate = brow >> 10;
    const int n = brow & 1023;
    const float* Wi2h = (gate == 0) ? Wii : (gate == 1) ? Wfi : (gate == 2) ? Wgi : Woi;
    const float* Wh2h = (gate == 0) ? Wih : (gate == 1) ? Wfh : (gate == 2) ? Wgh : Woh;
    const float* src = (k < 1024) ? (Wi2h + (int64_t)n * 1024 + k)
                                  : (Wh2h + (int64_t)n * 1024 + (k - 1024));
    f32x4 v0 = *(const f32x4*)src;
    f32x4 v1 = *(const f32x4*)(src + 4);
    u16x8 o;
    o[0] = f2bf(v0[0]); o[1] = f2bf(v0[1]); o[2] = f2bf(v0[2]); o[3] = f2bf(v0[3]);
    o[4] = f2bf(v1[0]); o[5] = f2bf(v1[1]); o[6] = f2bf(v1[2]); o[7] = f2bf(v1[3]);
    *(u16x8*)(B + off) = o;
}

// ---------------- GEMM: C(8192x4096 bf16 preact) = A(8192x2048) * B(4096x2048)^T ----------------
// m97 structure: 128x128 tile, BK=32, 4 waves (2x2), 4x4 16x16x32 frags/wave,
// global_load_lds width-16 staging, 2 barriers per K-step, XCD-swizzled blockIdx.
__global__ void __launch_bounds__(256) gemm_preact(
        const unsigned short* __restrict__ A,
        const unsigned short* __restrict__ Bw,
        unsigned short* __restrict__ C) {
    __shared__ __align__(16) unsigned short ldsA[128 * 32];
    __shared__ __align__(16) unsigned short ldsB[128 * 32];

    const int bid = blockIdx.x;                 // 2048 blocks, 2048 % 8 == 0 -> bijective swizzle
    const int swz = ((bid & 7) << 8) | (bid >> 3);
    const int bm = swz >> 5;                    // 64 M-blocks
    const int bn = swz & 31;                    // 32 N-blocks
    const int t = threadIdx.x;
    const int lane = t & 63;
    const int wave = t >> 6;
    const int wm = (wave >> 1) << 6;            // wave row offset (0/64)
    const int wn = (wave & 1) << 6;             // wave col offset (0/64)

    f32x4 acc[4][4];
#pragma unroll
    for (int m = 0; m < 4; ++m)
#pragma unroll
        for (int n = 0; n < 4; ++n)
            acc[m][n] = (f32x4){0.f, 0.f, 0.f, 0.f};

    // staging: tile is 128 rows x 32 bf16 (64 B/row) = 512 x 16B chunks; thread t does chunks t, t+256
    const int c0i = t;
    const int c1i = t + 256;
    const int64_t aOff0 = (int64_t)(bm * 128 + (c0i >> 2)) * KD + ((c0i & 3) << 3);
    const int64_t aOff1 = (int64_t)(bm * 128 + (c1i >> 2)) * KD + ((c1i & 3) << 3);
    const int64_t bOff0 = (int64_t)(bn * 128 + (c0i >> 2)) * KD + ((c0i & 3) << 3);
    const int64_t bOff1 = (int64_t)(bn * 128 + (c1i >> 2)) * KD + ((c1i & 3) << 3);
    unsigned short* lA0 = &ldsA[wave * 512];          // wave-uniform LDS bases (HW adds lane*16B)
    unsigned short* lA1 = &ldsA[2048 + wave * 512];
    unsigned short* lB0 = &ldsB[wave * 512];
    unsigned short* lB1 = &ldsB[2048 + wave * 512];

    const int r = lane & 15;
    const int kq = (lane >> 4) << 3;            // 8 contiguous k per lane

    for (int k0 = 0; k0 < KD; k0 += 32) {
        __syncthreads();                        // prior reads done before overwrite
        __builtin_amdgcn_global_load_lds((const gu32_t*)(A + aOff0 + k0), (lu32_t*)lA0, 16, 0, 0);
        __builtin_amdgcn_global_load_lds((const gu32_t*)(A + aOff1 + k0), (lu32_t*)lA1, 16, 0, 0);
        __builtin_amdgcn_global_load_lds((const gu32_t*)(Bw + bOff0 + k0), (lu32_t*)lB0, 16, 0, 0);
        __builtin_amdgcn_global_load_lds((const gu32_t*)(Bw + bOff1 + k0), (lu32_t*)lB1, 16, 0, 0);
        __syncthreads();                        // barrier drains vmcnt -> LDS valid

        bf16x8 af[4], bfr[4];
#pragma unroll
        for (int m = 0; m < 4; ++m)
            af[m] = *(const bf16x8*)&ldsA[(wm + m * 16 + r) * 32 + kq];
#pragma unroll
        for (int n = 0; n < 4; ++n)
            bfr[n] = *(const bf16x8*)&ldsB[(wn + n * 16 + r) * 32 + kq];
#pragma unroll
        for (int m = 0; m < 4; ++m)
#pragma unroll
            for (int n = 0; n < 4; ++n)
                acc[m][n] = __builtin_amdgcn_mfma_f32_16x16x32_bf16(af[m], bfr[n], acc[m][n], 0, 0, 0);
    }

    // C/D layout (verified m89/m91): col = lane&15, row = (lane>>4)*4 + j
    const int colBase = bn * 128 + wn + r;
    const int rowBase = bm * 128 + wm + ((lane >> 4) << 2);
#pragma unroll
    for (int m = 0; m < 4; ++m)
#pragma unroll
        for (int n = 0; n < 4; ++n) {
            const int col = colBase + n * 16;
#pragma unroll
            for (int j = 0; j < 4; ++j) {
                const int row = rowBase + m * 16 + j;
                C[(int64_t)row * ND + col] = f2bf(acc[m][n][j]);
            }
        }
}

// ---------------- elementwise LSTM cell ----------------
__global__ void __launch_bounds__(256) lstm_epilogue(
        const unsigned short* __restrict__ C,   // 8192 x 4096 bf16 preacts [i|f|g|o]
        const float* __restrict__ c0,
        const float* __restrict__ bii, const float* __restrict__ bih,
        const float* __restrict__ bfi, const float* __restrict__ bfh,
        const float* __restrict__ bgi, const float* __restrict__ bgh,
        const float* __restrict__ boi, const float* __restrict__ boh,
        float* __restrict__ out) {
    const int t = blockIdx.x * 256 + threadIdx.x;   // 2,097,152 threads, 4 elems each
    const int64_t e = (int64_t)t * 4;
    const int n = (int)(e & 1023);
    const int64_t cb = ((e >> 10) << 12) | n;        // row*4096 + n
    u16x4 pi = *(const u16x4*)&C[cb];
    u16x4 pf = *(const u16x4*)&C[cb + 1024];
    u16x4 pg = *(const u16x4*)&C[cb + 2048];
    u16x4 po = *(const u16x4*)&C[cb + 3072];
    f32x4 cv = *(const f32x4*)&c0[e];
    f32x4 b_i0 = *(const f32x4*)&bii[n], b_i1 = *(const f32x4*)&bih[n];
    f32x4 b_f0 = *(const f32x4*)&bfi[n], b_f1 = *(const f32x4*)&bfh[n];
    f32x4 b_g0 = *(const f32x4*)&bgi[n], b_g1 = *(const f32x4*)&bgh[n];
    f32x4 b_o0 = *(const f32x4*)&boi[n], b_o1 = *(const f32x4*)&boh[n];
    f32x4 ov, ctv;
#pragma unroll
    for (int j = 0; j < 4; ++j) {
        float it = sigmoidf_(bf2f(pi[j]) + b_i0[j] + b_i1[j]);
        float ft = sigmoidf_(bf2f(pf[j]) + b_f0[j] + b_f1[j]);
        float gt = tanhf_(bf2f(pg[j]) + b_g0[j] + b_g1[j]);
        float ot = sigmoidf_(bf2f(po[j]) + b_o0[j] + b_o1[j]);
        float ct = ft * cv[j] + it * gt;
        ctv[j] = ct;
        ov[j] = ot * tanhf_(ct);
    }
    *(f32x4*)&out[e] = ov;
    *(f32x4*)&out[(int64_t)BATCH * DH + e] = ctv;
}

extern "C" void kernel_launch(void* const* d_in, const int* in_sizes, int n_in,
                              void* d_out, int out_size, void* d_ws, size_t ws_size,
                              hipStream_t stream) {
    const float* x   = (const float*)d_in[0];
    const float* h0  = (const float*)d_in[1];
    const float* c0  = (const float*)d_in[2];
    const float* Wii = (const float*)d_in[3];
    const float* bii = (const float*)d_in[4];
    const float* Wih = (const float*)d_in[5];
    const float* bih = (const float*)d_in[6];
    const float* Wfi = (const float*)d_in[7];
    const float* bfi = (const float*)d_in[8];
    const float* Wfh = (const float*)d_in[9];
    const float* bfh = (const float*)d_in[10];
    const float* Wgi = (const float*)d_in[11];
    const float* bgi = (const float*)d_in[12];
    const float* Wgh = (const float*)d_in[13];
    const float* bgh = (const float*)d_in[14];
    const float* Woi = (const float*)d_in[15];
    const float* boi = (const float*)d_in[16];
    const float* Woh = (const float*)d_in[17];
    const float* boh = (const float*)d_in[18];

    // ws layout: A bf16 32MB | B bf16 16MB | C bf16 64MB  (112 MB total)
    unsigned short* A  = (unsigned short*)d_ws;
    unsigned short* Bw = A + (size_t)BATCH * KD;
    unsigned short* C  = Bw + (size_t)ND * KD;
    float* out = (float*)d_out;

    convert_A<<<8192, 256, 0, stream>>>(x, h0, A);
    convert_B<<<4096, 256, 0, stream>>>(Wii, Wih, Wfi, Wfh, Wgi, Wgh, Woi, Woh, Bw);
    gemm_preact<<<2048, 256, 0, stream>>>(A, Bw, C);
    lstm_epilogue<<<8192, 256, 0, stream>>>(C, c0, bii, bih, bfi, bfh, bgi, bgh, boi, boh, out);
}